// Round 4
// baseline (747.052 us; speedup 1.0000x reference)
//
#include <hip/hip_runtime.h>

typedef unsigned short ushort_t;
typedef __attribute__((ext_vector_type(4))) ushort_t ushort4_t;
typedef __attribute__((ext_vector_type(8))) short short8;
typedef __attribute__((ext_vector_type(4))) float f32x4;

#define TOKENS  4096
#define H_DIM   1024
#define HFF_DIM 4096
#define NEXP    8

// round-to-nearest-even f32 -> bf16
__device__ __forceinline__ ushort_t f2b(float f) {
    union { float f; unsigned u; } v; v.f = f;
    unsigned r = v.u + 0x7fffu + ((v.u >> 16) & 1u);
    return (ushort_t)(r >> 16);
}

// jax.nn.gelu default: approximate=True (tanh form)
__device__ __forceinline__ float gelu_tanh(float x) {
    float u = 0.7978845608028654f * (x + 0.044715f * x * x * x);
    return 0.5f * x * (1.0f + tanhf(u));
}

// ---------------- routing ----------------
__global__ void route_kernel(const float* __restrict__ probs,
                             const int* __restrict__ idx,
                             int* __restrict__ count,
                             int* __restrict__ token_id,
                             float* __restrict__ gate) {
    int t = blockIdx.x * blockDim.x + threadIdx.x;
    if (t >= TOKENS) return;
    int i0 = idx[t * 2 + 0];
    int i1 = idx[t * 2 + 1];
    float p0 = probs[t * 2 + 0];
    float p1 = probs[t * 2 + 1];
    if (i0 == i1) {
        float p = fmaxf(p0, p1);
        int pos = atomicAdd(&count[i0], 1);
        token_id[i0 * TOKENS + pos] = t;
        gate[i0 * TOKENS + pos] = p;
    } else {
        int pos = atomicAdd(&count[i0], 1);
        token_id[i0 * TOKENS + pos] = t;
        gate[i0 * TOKENS + pos] = p0;
        pos = atomicAdd(&count[i1], 1);
        token_id[i1 * TOKENS + pos] = t;
        gate[i1 * TOKENS + pos] = p1;
    }
}

__global__ void prefix_kernel(const int* __restrict__ count, int* __restrict__ offsets) {
    if (threadIdx.x == 0 && blockIdx.x == 0) {
        int acc = 0;
        for (int e = 0; e < NEXP; ++e) { offsets[e] = acc; acc += count[e]; }
        offsets[NEXP] = acc;
    }
}

// ---------------- branchless region-partitioned f32->bf16 cast ----------------
// blocks [0,512): x (1M float4); [512,4608): W1 (8.4M); [4608,8704): W2
__global__ __launch_bounds__(256) void cast_region(
        const float* __restrict__ x, ushort_t* __restrict__ xb,
        const float* __restrict__ W1, ushort_t* __restrict__ W1b,
        const float* __restrict__ W2, ushort_t* __restrict__ W2b) {
    int b = blockIdx.x;
    const float4* src; ushort4_t* dst; size_t base;
    if (b < 512)        { src = (const float4*)x;  dst = (ushort4_t*)xb;  base = (size_t)b * 2048; }
    else if (b < 4608)  { src = (const float4*)W1; dst = (ushort4_t*)W1b; base = (size_t)(b - 512) * 2048; }
    else                { src = (const float4*)W2; dst = (ushort4_t*)W2b; base = (size_t)(b - 4608) * 2048; }
    base += threadIdx.x;
#pragma unroll
    for (int j = 0; j < 8; ++j) {
        float4 v = src[base + j * 256];
        ushort4_t o;
        o.x = f2b(v.x); o.y = f2b(v.y); o.z = f2b(v.z); o.w = f2b(v.w);
        dst[base + j * 256] = o;
    }
}

// ================= BK=64 pipelined bf16 GEMMs =================
// LDS tile: [c(8 chunks of 8 k-elems)][row(128)][8 bf16] = 16 KB per matrix.
// Conflict-free (verified 0 conflicts R2/R3). Reg-prefetch next 64-k slab.

// GEMM1: h[slot] = gelu(xb[tok] . W1b[e]^T). 128x128 tile, BK=64, K=1024.
__global__ __launch_bounds__(256) void gemm1_fast(
        const ushort_t* __restrict__ xb, const ushort_t* __restrict__ W1b,
        const int* __restrict__ count, const int* __restrict__ offsets,
        const int* __restrict__ token_id, ushort_t* __restrict__ h) {
    const int e = blockIdx.z;
    const int cnt = count[e];
    const int mt = blockIdx.y;
    if (mt * 128 >= cnt) return;
    const int nt = blockIdx.x;
    const int base = offsets[e];

    __shared__ __align__(16) ushort_t As[8192];  // 16 KB
    __shared__ __align__(16) ushort_t Bs[8192];

    const int tid = threadIdx.x;
    const int row = tid & 127;
    const int half = tid >> 7;  // 0/1: which 32-k (64 B) slab of the row

    int am = mt * 128 + row;
    int amc = am < cnt ? am : (cnt - 1);   // clamp: garbage rows discarded in epilogue
    const int tok = token_id[e * TOKENS + amc];
    const ushort_t* aptr = xb + (size_t)tok * H_DIM + half * 32;
    const ushort_t* bptr = W1b + (size_t)e * HFF_DIM * H_DIM
                           + (size_t)(nt * 128 + row) * H_DIM + half * 32;

    ushort_t* aw = As + ((half * 4) * 128 + row) * 8;   // chunk stride 1024 elems
    ushort_t* bw = Bs + ((half * 4) * 128 + row) * 8;

    const int lane = tid & 63;
    const int wave = tid >> 6;
    const int wm = (wave >> 1) << 6;
    const int wn = (wave & 1) << 6;
    const int lr = lane & 15;
    const int lq = lane >> 4;

    f32x4 acc[4][4];
#pragma unroll
    for (int mi = 0; mi < 4; ++mi)
#pragma unroll
        for (int ni = 0; ni < 4; ++ni)
            acc[mi][ni] = (f32x4){0.f, 0.f, 0.f, 0.f};

    short8 ra[4], rb[4];
#pragma unroll
    for (int j = 0; j < 4; ++j) {
        ra[j] = *(const short8*)(aptr + j * 8);
        rb[j] = *(const short8*)(bptr + j * 8);
    }

    for (int k0 = 0; k0 < H_DIM; k0 += 64) {
        __syncthreads();
#pragma unroll
        for (int j = 0; j < 4; ++j) {
            *(short8*)(aw + j * 1024) = ra[j];
            *(short8*)(bw + j * 1024) = rb[j];
        }
        __syncthreads();

        if (k0 + 64 < H_DIM) {
#pragma unroll
            for (int j = 0; j < 4; ++j) {
                ra[j] = *(const short8*)(aptr + k0 + 64 + j * 8);
                rb[j] = *(const short8*)(bptr + k0 + 64 + j * 8);
            }
        }

#pragma unroll
        for (int kb = 0; kb < 2; ++kb) {
            short8 af[4], bf[4];
            const int c = (kb * 4 + lq) * 128;
#pragma unroll
            for (int mi = 0; mi < 4; ++mi)
                af[mi] = *(const short8*)&As[(c + wm + mi * 16 + lr) * 8];
#pragma unroll
            for (int ni = 0; ni < 4; ++ni)
                bf[ni] = *(const short8*)&Bs[(c + wn + ni * 16 + lr) * 8];
#pragma unroll
            for (int mi = 0; mi < 4; ++mi)
#pragma unroll
                for (int ni = 0; ni < 4; ++ni)
                    acc[mi][ni] = __builtin_amdgcn_mfma_f32_16x16x32_bf16(
                        af[mi], bf[ni], acc[mi][ni], 0, 0, 0);
        }
    }

#pragma unroll
    for (int mi = 0; mi < 4; ++mi) {
#pragma unroll
        for (int r = 0; r < 4; ++r) {
            int m = mt * 128 + wm + mi * 16 + lq * 4 + r;
            if (m < cnt) {
                ushort_t* hp = h + (size_t)(base + m) * HFF_DIM + nt * 128 + wn + lr;
#pragma unroll
                for (int ni = 0; ni < 4; ++ni)
                    hp[ni * 16] = f2b(gelu_tanh(acc[mi][ni][r]));
            }
        }
    }
}

// GEMM2: out[tok] += gate * (h[slot] . W2b[e]^T). 128x128 tile, BK=64,
// K split in 4 chunks of 1024 (blockIdx.z = e*4+kz).
__global__ __launch_bounds__(256) void gemm2_fast(
        const ushort_t* __restrict__ h, const ushort_t* __restrict__ W2b,
        const int* __restrict__ count, const int* __restrict__ offsets,
        const int* __restrict__ token_id, const float* __restrict__ gate,
        float* __restrict__ out) {
    const int e = blockIdx.z >> 2;
    const int kz = blockIdx.z & 3;
    const int cnt = count[e];
    const int mt = blockIdx.y;
    if (mt * 128 >= cnt) return;
    const int nt = blockIdx.x;
    const int base = offsets[e];
    const int kbeg = kz * (HFF_DIM / 4);
    const int kend = kbeg + (HFF_DIM / 4);

    __shared__ __align__(16) ushort_t As[8192];
    __shared__ __align__(16) ushort_t Bs[8192];

    const int tid = threadIdx.x;
    const int row = tid & 127;
    const int half = tid >> 7;

    // h padded by 128 rows: base+mt*128+row always in-bounds
    const ushort_t* aptr = h + (size_t)(base + mt * 128 + row) * HFF_DIM + half * 32;
    const ushort_t* bptr = W2b + (size_t)e * H_DIM * HFF_DIM
                           + (size_t)(nt * 128 + row) * HFF_DIM + half * 32;

    ushort_t* aw = As + ((half * 4) * 128 + row) * 8;
    ushort_t* bw = Bs + ((half * 4) * 128 + row) * 8;

    const int lane = tid & 63;
    const int wave = tid >> 6;
    const int wm = (wave >> 1) << 6;
    const int wn = (wave & 1) << 6;
    const int lr = lane & 15;
    const int lq = lane >> 4;

    f32x4 acc[4][4];
#pragma unroll
    for (int mi = 0; mi < 4; ++mi)
#pragma unroll
        for (int ni = 0; ni < 4; ++ni)
            acc[mi][ni] = (f32x4){0.f, 0.f, 0.f, 0.f};

    short8 ra[4], rb[4];
#pragma unroll
    for (int j = 0; j < 4; ++j) {
        ra[j] = *(const short8*)(aptr + kbeg + j * 8);
        rb[j] = *(const short8*)(bptr + kbeg + j * 8);
    }

    for (int k0 = kbeg; k0 < kend; k0 += 64) {
        __syncthreads();
#pragma unroll
        for (int j = 0; j < 4; ++j) {
            *(short8*)(aw + j * 1024) = ra[j];
            *(short8*)(bw + j * 1024) = rb[j];
        }
        __syncthreads();

        if (k0 + 64 < kend) {
#pragma unroll
            for (int j = 0; j < 4; ++j) {
                ra[j] = *(const short8*)(aptr + k0 + 64 + j * 8);
                rb[j] = *(const short8*)(bptr + k0 + 64 + j * 8);
            }
        }

#pragma unroll
        for (int kb = 0; kb < 2; ++kb) {
            short8 af[4], bf[4];
            const int c = (kb * 4 + lq) * 128;
#pragma unroll
            for (int mi = 0; mi < 4; ++mi)
                af[mi] = *(const short8*)&As[(c + wm + mi * 16 + lr) * 8];
#pragma unroll
            for (int ni = 0; ni < 4; ++ni)
                bf[ni] = *(const short8*)&Bs[(c + wn + ni * 16 + lr) * 8];
#pragma unroll
            for (int mi = 0; mi < 4; ++mi)
#pragma unroll
                for (int ni = 0; ni < 4; ++ni)
                    acc[mi][ni] = __builtin_amdgcn_mfma_f32_16x16x32_bf16(
                        af[mi], bf[ni], acc[mi][ni], 0, 0, 0);
        }
    }

#pragma unroll
    for (int mi = 0; mi < 4; ++mi) {
#pragma unroll
        for (int r = 0; r < 4; ++r) {
            int m = mt * 128 + wm + mi * 16 + lq * 4 + r;
            if (m < cnt) {
                int tok = token_id[e * TOKENS + m];
                float g = gate[e * TOKENS + m];
                float* op = out + (size_t)tok * H_DIM + nt * 128 + wn + lr;
#pragma unroll
                for (int ni = 0; ni < 4; ++ni)
                    atomicAdd(&op[ni * 16], g * acc[mi][ni][r]);
            }
        }
    }
}

extern "C" void kernel_launch(void* const* d_in, const int* in_sizes, int n_in,
                              void* d_out, int out_size, void* d_ws, size_t ws_size,
                              hipStream_t stream) {
    const float* x     = (const float*)d_in[0];
    const float* probs = (const float*)d_in[1];
    const int*   idx   = (const int*)d_in[2];
    const float* W1    = (const float*)d_in[3];
    const float* W2    = (const float*)d_in[4];
    float* out = (float*)d_out;

    char* ws = (char*)d_ws;
    int*   count    = (int*)ws;                            // 8 ints
    int*   offsets  = (int*)(ws + 64);                     // 9 ints
    int*   token_id = (int*)(ws + 4096);                   // 128 KB
    float* gate     = (float*)(ws + 4096 + 8 * 4096 * 4);  // 128 KB

    const size_t XB_OFF  = 1ull << 20;                     // 8 MB
    const size_t W1B_OFF = 16ull << 20;                    // 64 MB
    const size_t W2B_OFF = 84ull << 20;                    // 64 MB
    const size_t H_OFF   = 156ull << 20;                   // (8192+128)*4096*2 = 65 MB

    ushort_t* xb  = (ushort_t*)(ws + XB_OFF);
    ushort_t* W1b = (ushort_t*)(ws + W1B_OFF);
    ushort_t* W2b = (ushort_t*)(ws + W2B_OFF);
    ushort_t* h   = (ushort_t*)(ws + H_OFF);

    hipMemsetAsync(count, 0, 64, stream);
    hipMemsetAsync(out, 0, (size_t)out_size * sizeof(float), stream);

    route_kernel<<<TOKENS / 256, 256, 0, stream>>>(probs, idx, count, token_id, gate);
    prefix_kernel<<<1, 64, 0, stream>>>(count, offsets);

    cast_region<<<8704, 256, 0, stream>>>(x, xb, W1, W1b, W2, W2b);

    dim3 g1(HFF_DIM / 128, TOKENS / 128, NEXP);
    gemm1_fast<<<g1, 256, 0, stream>>>(xb, W1b, count, offsets, token_id, h);

    dim3 g2(H_DIM / 128, TOKENS / 128, NEXP * 4);
    gemm2_fast<<<g2, 256, 0, stream>>>(h, W2b, count, offsets, token_id, gate, out);
}